// Round 8
// baseline (1206.223 us; speedup 1.0000x reference)
//
// EncoderDecoder1DBlock on MI355X (gfx950).
// Int8 fake-quant reproduced EXACTLY via integer-valued bf16 MFMA GEMMs.
// R16: per-shape GEMM configs + MLP2 K-split.
//  R15 post-mortem: 128x128 tiles REGRESSED the N=1024 GEMMs (MLP2
//  77us@R13 -> 89us@R15): grid 256 = 1 block/CU, all waves lockstep on
//  the per-K-step barrier -> no cross-block latency hiding. Fix:
//  - gemm_kernel gains WAVES param. N=1024 GEMMs back to R13-proven
//    <64,128,64>/4-wave/256thr (512 blocks, 3 blocks/CU). Wide GEMMs
//    (QKV/crossKV/MLP1) keep <64,128,128>/8-wave.
//  - MLP2 (K=4096, 64 latency-bound iters) K-split z=2 via existing
//    z-offsets (oA2=oB2=2048, oC2=4M elems): 1024 blocks, 32 iters,
//    partials in dead BIGF region; addout_kernel fuses C0+C1+B2+resid.
//    (fp32 reassociation only; absmax margin 2.4x.)
// fattn + quant unchanged from R13/R14 (passed, absmax 0.0508).
// Workspace: 161 MB.

#include <hip/hip_runtime.h>
#include <hip/hip_bf16.h>

typedef __hip_bfloat16 bf16;
typedef __attribute__((ext_vector_type(8))) short bf16x8;   // 8 bf16 = 4 VGPRs
typedef __attribute__((ext_vector_type(4))) float floatx4;
typedef __attribute__((ext_vector_type(2))) unsigned uintx2;

#define NBATCH 8
#define SEQ    512
#define DIM    1024
#define NHEAD  16
#define DHEAD  64
#define FF     4096
#define NTOK   (NBATCH*SEQ)            // 4096
#define NROW   (NBATCH*NHEAD*SEQ)      // 65536 attention rows

template<bool B> struct BoolC { static constexpr bool value = B; };

__device__ inline void atomicMaxF(float* p, float v){ atomicMax((unsigned int*)p, __float_as_uint(v)); } // v >= 0

// async global->LDS, 16 bytes per lane (LDS dest = wave-uniform base + lane*16)
__device__ inline void gld16(bf16* lds, const bf16* g){
  __builtin_amdgcn_global_load_lds(
      (const __attribute__((address_space(1))) void*)g,
      (__attribute__((address_space(3))) void*)lds, 16, 0, 0);
}

__device__ inline unsigned pack2bf(float a, float b){
  bf16 ha = __float2bfloat16(a), hb = __float2bfloat16(b);
  unsigned short ua, ub;
  __builtin_memcpy(&ua, &ha, 2); __builtin_memcpy(&ub, &hb, 2);
  return ((unsigned)ub << 16) | (unsigned)ua;
}

// ---- 64-way stripe: sub-slot j lives at stripe[j*16] (64B apart) ----
__device__ inline float stripe_max(const float* __restrict__ st){
  float v = st[(threadIdx.x & 63)*16];
#pragma unroll
  for (int o = 32; o > 0; o >>= 1) v = fmaxf(v, __shfl_xor(v, o));
  return v;
}
__device__ inline float stripe_min(const float* __restrict__ st){
  float v = st[(threadIdx.x & 63)*16];
#pragma unroll
  for (int o = 32; o > 0; o >>= 1) v = fminf(v, __shfl_xor(v, o));
  return v;
}

// blockDim.x == 256 assumed (4 waves). OP: 0=sum, 1=max, 2=min
template<int OP>
__device__ inline float block_reduce256(float v){
  __shared__ float red[4];
#pragma unroll
  for (int o = 32; o > 0; o >>= 1){
    float t = __shfl_down(v, o);
    v = OP==0 ? v + t : (OP==1 ? fmaxf(v, t) : fminf(v, t));
  }
  int lane = threadIdx.x & 63, w = threadIdx.x >> 6;
  if (lane == 0) red[w] = v;
  __syncthreads();
  float r = OP==0 ? (red[0]+red[1])+(red[2]+red[3])
          : OP==1 ? fmaxf(fmaxf(red[0],red[1]), fmaxf(red[2],red[3]))
                  : fminf(fminf(red[0],red[1]), fminf(red[2],red[3]));
  __syncthreads();
  return r;
}

// ---- stats init ----
__global__ void init_kernel(float* __restrict__ ST){
  int i = blockIdx.x * 256 + threadIdx.x;
  if (i >= 32768) return;
  ST[i] = (i >= 16384 && i < 18432) ? 3.402823466e38f : 0.0f;
}

// per-column |w| max (raw, atomic across row-chunks of 128)
__global__ void colamax_kernel(const float* __restrict__ w, int K, int N, float* __restrict__ raw){
  int c = blockIdx.x * 256 + threadIdx.x;
  if (c >= N) return;
  int r0 = blockIdx.y * 128;
  float m = 0.0f;
  for (int r = r0; r < r0 + 128; ++r) m = fmaxf(m, fabsf(w[(size_t)r * N + c]));
  atomicMaxF(&raw[c], m);
}

__global__ void finalize_kernel(float* __restrict__ p, int n){
  int i = blockIdx.x * 256 + threadIdx.x;
  if (i < n) p[i] = fmaxf(p[i] * (1.0f/127.0f), 1e-6f);
}

// LayerNorm (row of 1024) + striped amax of output
__global__ void ln_kernel(const float* __restrict__ x, const float* __restrict__ g,
                          const float* __restrict__ bb, float* __restrict__ out,
                          float* __restrict__ stripe){
  int row = blockIdx.x, tid = threadIdx.x;
  const float* xr = x + (size_t)row * DIM;
  float v[4];
#pragma unroll
  for (int i = 0; i < 4; i++) v[i] = xr[tid + i*256];
  float s = (v[0]+v[1]) + (v[2]+v[3]);
  s = block_reduce256<0>(s);
  float mean = s * (1.0f/DIM);
  float sq = 0.f;
#pragma unroll
  for (int i = 0; i < 4; i++){ float d = v[i]-mean; sq += d*d; }
  sq = block_reduce256<0>(sq);
  float inv = 1.0f / sqrtf(sq * (1.0f/DIM) + 1e-6f);
  float am = 0.f;
  float* orow = out + (size_t)row * DIM;
#pragma unroll
  for (int i = 0; i < 4; i++){
    int c = tid + i*256;
    float o = (v[i]-mean)*inv*g[c] + bb[c];
    orow[c] = o;
    am = fmaxf(am, fabsf(o));
  }
  am = block_reduce256<1>(am);
  if (tid == 0) atomicMaxF(&stripe[(blockIdx.x & 63)*16], am);
}

__global__ void amax_kernel(const float* __restrict__ x, long n, float* __restrict__ stripe){
  long i = (long)blockIdx.x * 256 + threadIdx.x;
  long st = (long)gridDim.x * 256;
  float m = 0.f;
  for (; i < n; i += st) m = fmaxf(m, fabsf(x[i]));
  m = block_reduce256<1>(m);
  if (threadIdx.x == 0) atomicMaxF(&stripe[(blockIdx.x & 63)*16], m);
}

// elementwise quantize to integer-valued bf16 (vectorized: 4 elems/thread)
__global__ void quant_kernel(const float* __restrict__ in, bf16* __restrict__ outq,
                             const float* __restrict__ stripe, float* __restrict__ scale_out, long n4){
  float s = fmaxf(stripe_max(stripe) * (1.0f/127.0f), 1e-6f);
  long i = (long)blockIdx.x * 256 + threadIdx.x;
  if (i == 0) scale_out[0] = s;
  long st = (long)gridDim.x * 256;
  for (; i < n4; i += st){
    floatx4 v = ((const floatx4*)in)[i];
    float q[4];
#pragma unroll
    for (int j = 0; j < 4; j++) q[j] = rintf(fminf(fmaxf(v[j] / s, -127.0f), 127.0f));
    uintx2 o; o[0] = pack2bf(q[0], q[1]); o[1] = pack2bf(q[2], q[3]);
    ((uintx2*)outq)[i] = o;
  }
}

// OUT = C0 + C1 + bias + resid (MLP2 K-split merge), float4 vectorized
__global__ void addout_kernel(const float* __restrict__ C0, const float* __restrict__ C1,
                              const float* __restrict__ R, const float* __restrict__ bias,
                              float* __restrict__ OUT, long n4){
  long i = (long)blockIdx.x * 256 + threadIdx.x;
  long st = (long)gridDim.x * 256;
  for (; i < n4; i += st){
    floatx4 a = ((const floatx4*)C0)[i];
    floatx4 b = ((const floatx4*)C1)[i];
    floatx4 bv = ((const floatx4*)bias)[i & (DIM/4 - 1)];
    floatx4 r = ((const floatx4*)R)[i];
    floatx4 o;
#pragma unroll
    for (int j = 0; j < 4; j++) o[j] = ((a[j] + b[j]) + bv[j]) + r[j];
    ((floatx4*)OUT)[i] = o;
  }
}

// weight quantize + transpose: w[K][N] -> wqT[N][K]
__global__ void transq_kernel(const float* __restrict__ w, bf16* __restrict__ wqT,
                              const float* __restrict__ scales, int K, int N){
  __shared__ float tile[32][33];
  int c0 = blockIdx.x * 32, r0 = blockIdx.y * 32;
  int tx = threadIdx.x, ty = threadIdx.y;   // (32,8)
#pragma unroll
  for (int i = 0; i < 4; i++){
    int r = ty + i*8;
    tile[r][tx] = w[(size_t)(r0 + r) * N + c0 + tx];
  }
  __syncthreads();
#pragma unroll
  for (int i = 0; i < 4; i++){
    int cl = ty + i*8;
    float s = scales[c0 + cl];
    float q = rintf(fminf(fmaxf(tile[tx][cl] / s, -127.0f), 127.0f));
    wqT[(size_t)(c0 + cl) * K + r0 + tx] = __float2bfloat16(q);
  }
}

// V quantize + transpose: v f32 (B,S,H,DH) -> vqT bf16 (B*H, DH, S)
__global__ void vtransq_kernel(const float* __restrict__ v, bf16* __restrict__ vqT,
                               const float* __restrict__ stripe, float* __restrict__ scale_out){
  __shared__ float tile[64][65];
  float s = fmaxf(stripe_max(stripe) * (1.0f/127.0f), 1e-6f);
  int tx = threadIdx.x, ty = threadIdx.y;   // (64,8)
  int bh = blockIdx.y, j0 = blockIdx.x * 64;
  int b = bh >> 4, h = bh & 15;
  if (blockIdx.x == 0 && bh == 0 && tx == 0 && ty == 0) scale_out[0] = s;
#pragma unroll
  for (int i = 0; i < 8; i++){
    int j = j0 + ty + i*8;
    tile[ty + i*8][tx] = v[((size_t)((size_t)b*SEQ + j)*NHEAD + h)*DHEAD + tx];
  }
  __syncthreads();
#pragma unroll
  for (int i = 0; i < 8; i++){
    int d = ty + i*8;
    float q = rintf(fminf(fmaxf(tile[tx][d] / s, -127.0f), 127.0f));
    vqT[((size_t)bh*DHEAD + d)*SEQ + j0 + tx] = __float2bfloat16(q);
  }
}

// reduce min over lrow[0..n) into 64 stripe slots
__global__ void minl_kernel(const float* __restrict__ lrow, int n, float* __restrict__ stripe){
  float v = 3.402823466e38f;
  for (int i = blockIdx.x * 256 + threadIdx.x; i < n; i += 64*256) v = fminf(v, lrow[i]);
  v = block_reduce256<2>(v);
  if (threadIdx.x == 0) stripe[blockIdx.x*16] = v;
}

// =============== fused flash-style quantized attention (bf16 MFMA) =========
// grid (bh=128, half=2): 256 blocks = exactly 1/CU, ONE round. 512 threads
// = 8 waves x 32 Q rows. Block half h covers bands {h, 3-h}: waves 0-3 ->
// band h, waves 4-7 -> band 3-h (causal work per block balanced; the two
// blocks sharing a bh are 128 apart in linear id -> same XCD L2).
// K[512][64] (and V^T[64][512], MODE!=0) LDS-resident, XOR content swizzle
// (<=2-way bank alias = free). Swapped QK^T: K = A-operand, Q (regs) = B
// -> lane's S col = its Q row; row reduce = 2 shfl_xor. 3-pass softmax
// (max / sum / quantize+PV); exp via __expf (hw v_exp; P is integer-
// quantized after exp so 2e-7 rel error is harmless). Per-wave 16-row
// P tile (2KB) reused across jt.
// MODE 2 (self, CAUSAL): sp = 1/127 exactly.
// MODE 0 (cross stats): K-only LDS, writes (m,l) per row.
// MODE 1 (cross PV): stored stats; sp from minl stripe.
template<int MODE, bool CAUSAL>
__global__ __launch_bounds__(512, 2) void fattn_kernel(
    const bf16* __restrict__ Qq, const bf16* __restrict__ Kq,
    const bf16* __restrict__ VT, float* __restrict__ O,
    float* __restrict__ mrow, float* __restrict__ lrow,
    const float* __restrict__ sqp, const float* __restrict__ skp,
    const float* __restrict__ svp, const float* __restrict__ minl_stripe,
    float* __restrict__ amax_stripe)
{
  constexpr int LDSK = SEQ*DHEAD;                    // 32768 elems (64KB)
  constexpr int LDSV = (MODE==0) ? 0 : DHEAD*SEQ;    // 64KB
  constexpr int LDSP = (MODE==0) ? 0 : 8*16*DHEAD;   // 16KB (8 waves x 16x64 x2B)
  __shared__ __align__(16) bf16 smem[LDSK + LDSV + LDSP];
  bf16* Klds = smem;
  bf16* Vlds = smem + LDSK;
  char* Pw   = (char*)(smem + LDSK + LDSV);

  int bh = blockIdx.x, half = blockIdx.y;
  int b = bh >> 4, h = bh & 15;
  int tid = threadIdx.x, lane = tid & 63, w = tid >> 6;
  int l15 = lane & 15, g4 = lane >> 4;

  float sc = sqp[0] * skp[0];                        // logit scale

  // ---- stage K; XOR content swizzle on source ----
  for (int s = tid; s < SEQ*8; s += 512){            // 4096 slots
    int row = s >> 3, pc = s & 7;
    gld16(&Klds[s*8], Kq + ((size_t)(b*SEQ + row))*DIM + h*DHEAD + ((pc ^ (row & 7))<<3));
  }
  if (MODE != 0){
    const bf16* vbh = VT + (size_t)bh*DHEAD*SEQ;
    for (int s = tid; s < DHEAD*64; s += 512){       // 4096 slots
      int row = s >> 6, pc = s & 63;
      gld16(&Vlds[s*8], vbh + (size_t)row*SEQ + ((pc ^ (row & 7))<<3));
    }
  }

  // ---- wave's 32-row base: bands {half, 3-half} ----
  int band = (w < 4) ? half : (3 - half);
  int qb = band*128 + (w & 3)*32;

  // ---- Q fragments (B-operand: lane holds Q row qb+jt*16+l15) ----
  bf16x8 qf[2][2];
#pragma unroll
  for (int jt = 0; jt < 2; jt++)
#pragma unroll
    for (int ks = 0; ks < 2; ks++)
      qf[jt][ks] = *(const bf16x8*)(Qq + ((size_t)(b*SEQ + qb + jt*16 + l15))*DIM
                                       + h*DHEAD + ks*32 + g4*8);

  __syncthreads();                                   // drains global_load_lds

  int nkb   = CAUSAL ? ((qb + 95) >> 6) : (SEQ/64);  // blocks touched
  int kfull = CAUSAL ? (qb >> 6)        : (SEQ/64);  // fully-valid blocks
  int qs0 = qb + l15;                                // seq pos for jt=0 (+16 for jt=1)

  auto computeS = [&](int kb, floatx4 (&sacc)[4][2]){
#pragma unroll
    for (int it = 0; it < 4; it++)
#pragma unroll
      for (int jt = 0; jt < 2; jt++){ floatx4 zv = {0.f,0.f,0.f,0.f}; sacc[it][jt] = zv; }
#pragma unroll
    for (int ks = 0; ks < 2; ks++){
      bf16x8 af[4];
#pragma unroll
      for (int it = 0; it < 4; it++){
        int row = kb*64 + it*16 + l15;
        int pc  = (ks*4 + g4) ^ (row & 7);
        af[it] = *(const bf16x8*)(Klds + row*64 + pc*8);
      }
#pragma unroll
      for (int it = 0; it < 4; it++)
#pragma unroll
        for (int jt = 0; jt < 2; jt++)
          sacc[it][jt] = __builtin_amdgcn_mfma_f32_16x16x32_bf16(af[it], qf[jt][ks], sacc[it][jt], 0, 0, 0);
    }
  };

  float ml[2], ll[2];
  if (MODE != 1){
    // ---- pass 1: raw row max (full blocks unmasked, diagonal masked) ----
    float mr0 = -3.402823466e38f, mr1 = -3.402823466e38f;
    for (int kb = 0; kb < kfull; kb++){
      floatx4 sacc[4][2];
      computeS(kb, sacc);
#pragma unroll
      for (int it = 0; it < 4; it++)
#pragma unroll
        for (int r = 0; r < 4; r++){
          mr0 = fmaxf(mr0, sacc[it][0][r]);
          mr1 = fmaxf(mr1, sacc[it][1][r]);
        }
    }
    for (int kb = kfull; kb < nkb; kb++){
      floatx4 sacc[4][2];
      computeS(kb, sacc);
#pragma unroll
      for (int it = 0; it < 4; it++){
        int key = kb*64 + it*16 + g4*4;
#pragma unroll
        for (int r = 0; r < 4; r++){
          if (key + r <= qs0)      mr0 = fmaxf(mr0, sacc[it][0][r]);
          if (key + r <= qs0 + 16) mr1 = fmaxf(mr1, sacc[it][1][r]);
        }
      }
    }
    mr0 = fmaxf(mr0, __shfl_xor(mr0, 16)); mr0 = fmaxf(mr0, __shfl_xor(mr0, 32));
    mr1 = fmaxf(mr1, __shfl_xor(mr1, 16)); mr1 = fmaxf(mr1, __shfl_xor(mr1, 32));
    ml[0] = sc*mr0; ml[1] = sc*mr1;                  // logit-space max
    // ---- pass 2: row sum of exp ----
    float l0 = 0.f, l1 = 0.f;
    for (int kb = 0; kb < kfull; kb++){
      floatx4 sacc[4][2];
      computeS(kb, sacc);
#pragma unroll
      for (int it = 0; it < 4; it++)
#pragma unroll
        for (int r = 0; r < 4; r++){
          l0 += __expf(sc*sacc[it][0][r] - ml[0]);
          l1 += __expf(sc*sacc[it][1][r] - ml[1]);
        }
    }
    for (int kb = kfull; kb < nkb; kb++){
      floatx4 sacc[4][2];
      computeS(kb, sacc);
#pragma unroll
      for (int it = 0; it < 4; it++){
        int key = kb*64 + it*16 + g4*4;
#pragma unroll
        for (int r = 0; r < 4; r++){
          if (key + r <= qs0)      l0 += __expf(sc*sacc[it][0][r] - ml[0]);
          if (key + r <= qs0 + 16) l1 += __expf(sc*sacc[it][1][r] - ml[1]);
        }
      }
    }
    l0 += __shfl_xor(l0, 16); l0 += __shfl_xor(l0, 32);
    l1 += __shfl_xor(l1, 16); l1 += __shfl_xor(l1, 32);
    ll[0] = l0; ll[1] = l1;
    if (MODE == 0){
      if (g4 == 0){
        int ridx = bh*SEQ + qb + l15;
        mrow[ridx]      = ml[0]; lrow[ridx]      = ll[0];
        mrow[ridx + 16] = ml[1]; lrow[ridx + 16] = ll[1];
      }
      return;
    }
  } else {
    int ridx = bh*SEQ + qb + l15;
    ml[0] = mrow[ridx];      ll[0] = lrow[ridx];
    ml[1] = mrow[ridx + 16]; ll[1] = lrow[ridx + 16];
  }

  // ---- pass 3: quantize P + PV (per-wave 16-row P tile, jt loop) ----
  float sv = svp[0];
  float sp = (MODE == 2) ? (1.0f/127.0f)
           : fmaxf((1.0f/stripe_min(minl_stripe)) * (1.0f/127.0f), 1e-6f);
  float inv0 = 1.0f/ll[0], inv1 = 1.0f/ll[1];        // self path replicates e*inv/sp

  floatx4 oacc[2][4];
#pragma unroll
  for (int i = 0; i < 2; i++)
#pragma unroll
    for (int j = 0; j < 4; j++){ floatx4 zv = {0.f,0.f,0.f,0.f}; oacc[i][j] = zv; }

  char* Pme = Pw + w*(16*128);                       // wave-private 2KB tile

  auto pass3 = [&](int kb, auto mk){
    constexpr bool M = decltype(mk)::value;
    floatx4 sacc[4][2];
    computeS(kb, sacc);
#pragma unroll
    for (int jt = 0; jt < 2; jt++){
      int qsj = qs0 + jt*16;
      float mlj = ml[jt];
      float invj = jt ? inv1 : inv0;
      float llj = ll[jt];
      // quantize + write P[q=l15][key] (16-row tile, XOR piece swizzle)
#pragma unroll
      for (int it = 0; it < 4; it++){
        int k0 = it*16 + g4*4;
        float qv[4];
#pragma unroll
        for (int r = 0; r < 4; r++){
          bool ok = !M || (kb*64 + k0 + r) <= qsj;
          if (ok){
            float e = __expf(sc*sacc[it][jt][r] - mlj);
            float p = (MODE == 2) ? e * invj : e / llj;
            qv[r] = rintf(fminf(p / sp, 127.0f));
          } else qv[r] = 0.0f;
        }
        int bse = l15*128;
        *(unsigned*)(Pme + bse + ((((k0>>3) ^ (l15&7))<<4) | ((k0&7)<<1))) = pack2bf(qv[0], qv[1]);
        int k2 = k0 + 2;
        *(unsigned*)(Pme + bse + ((((k2>>3) ^ (l15&7))<<4) | ((k2&7)<<1))) = pack2bf(qv[2], qv[3]);
      }
      // PV accumulate: A = P (16 q rows), B = V^T (d cols), K = 64 keys
#pragma unroll
      for (int ks = 0; ks < 2; ks++){
        int kp = (ks*4 + g4) ^ (l15 & 7);
        bf16x8 pa = *(const bf16x8*)(Pme + l15*128 + kp*16);
#pragma unroll
        for (int fj = 0; fj < 4; fj++){
          int d = fj*16 + l15;
          int gp = kb*8 + ks*4 + g4;
          bf16x8 vf = *(const bf16x8*)((char*)Vlds + d*1024 + ((gp ^ (d & 7))<<4));
          oacc[jt][fj] = __builtin_amdgcn_mfma_f32_16x16x32_bf16(pa, vf, oacc[jt][fj], 0, 0, 0);
        }
      }
    }
  };
  for (int kb = 0; kb < kfull; kb++) pass3(kb, BoolC<false>{});
  for (int kb = kfull; kb < nkb; kb++) pass3(kb, BoolC<true>{});

  // ---- epilogue: O = oacc * sp * sv, striped amax ----
  float osc = sp * sv;
  float am = 0.0f;
#pragma unroll
  for (int jt = 0; jt < 2; jt++){
    int qrow = qb + jt*16 + g4*4;
#pragma unroll
    for (int fj = 0; fj < 4; fj++){
      int d = fj*16 + l15;
#pragma unroll
      for (int r = 0; r < 4; r++){
        float v = oacc[jt][fj][r] * osc;
        O[((size_t)(b*SEQ + qrow + r))*DIM + h*DHEAD + d] = v;
        am = fmaxf(am, fabsf(v));
      }
    }
  }
#pragma unroll
  for (int o = 32; o > 0; o >>= 1) am = fmaxf(am, __shfl_down(am, o));
  if (lane == 0){
    int j = (blockIdx.x*5 + blockIdx.y*11 + w) & 63;
    atomicMaxF(&amax_stripe[j*16], am);
  }
}

// ------- MFMA GEMM (TM x TN tile, async dbuf, XCD + LDS-XOR swizzled) ------
// WAVES=4: 256 thr, 2x2 wave grid, wave tile (TM/2)x(TN/2)  [R13-proven]
// WAVES=8: 512 thr, 2x4 wave grid, wave tile (TM/2)x(TN/4)  [R15-proven]
// LDS layout: slot (row,pc) holds global piece pc^(row&(PIECES-1)); readers
// apply the inverse so quarter-wave ds_read_b128 banks spread 2-way (free).
template<int BK, int TM, int TN, int WAVES, int RESID, bool CAUSAL, bool RELU, bool HASBIAS, bool HASAMAX, bool SPLITN>
__global__ __launch_bounds__(WAVES*64) void gemm_kernel(
    const bf16* __restrict__ A, const bf16* __restrict__ Bt,
    float* __restrict__ C, const float* __restrict__ R,
    const float* __restrict__ sAp, const float* __restrict__ sBp, int sBstride,
    const float* __restrict__ bias, float post, float* __restrict__ amax_stripe,
    int Mdim, int Ndim, int Kdim, int lda, int ldb, int ldc,
    long oA1, long oA2, long oB1, long oB2, long oC1, long oC2, long oCchunk)
{
  const int NT  = WAVES*64;
  const int WCG = WAVES/2;             // col groups (2 or 4); 2 row groups
  const int FI  = TM/32, FJ = TN/(16*WCG);
  const int PIECES = BK/8;             // 16B pieces per row
  const int PMASK  = PIECES - 1;
  __shared__ __align__(16) bf16 As[2][TM*BK];
  __shared__ __align__(16) bf16 Bs[2][TN*BK];
  int z = blockIdx.z;
  long offA = (long)(z >> 4)*oA1 + (long)(z & 15)*oA2;
  long offB = (long)(z >> 4)*oB1 + (long)(z & 15)*oB2;
  long offC = (long)(z >> 4)*oC1 + (long)(z & 15)*oC2;
  const bf16* Ab = A + offA;
  const bf16* Bb = Bt + offB;
  int tid = threadIdx.x;
  int lane = tid & 63, wid = tid >> 6;
  int wr = wid / WCG, wc = wid % WCG;

  // XCD-aware swizzle: round-robin linear-id -> give XCD k a row band.
  int bx = blockIdx.x, by = blockIdx.y;
  if ((gridDim.y & 7) == 0){
    int lin  = by * gridDim.x + bx;
    int xcd  = lin & 7, slot = lin >> 3;
    int bandH = gridDim.y >> 3;
    by = xcd * bandH + (slot % bandH);
    bx = slot / bandH;
  }
  int m0 = by * TM, n0 = bx * TN;

  floatx4 acc[FI][FJ];
#pragma unroll
  for (int i = 0; i < FI; i++)
#pragma unroll
    for (int j = 0; j < FJ; j++){ floatx4 zv = {0.f,0.f,0.f,0.f}; acc[i][j] = zv; }

  const int SLOTSA = TM*PIECES;
  const int SLOTSB = TN*PIECES;
  bool skip = CAUSAL && (n0 > m0 + TM - 1);

  auto stage = [&](int kt, int buf){
#pragma unroll
    for (int s = tid; s < SLOTSA; s += NT){
      int row = s / PIECES, pc = s % PIECES;
      int gpc = pc ^ (row & PMASK);                 // XOR content swizzle
      int gm = m0 + row; if (gm > Mdim-1) gm = Mdim-1;
      gld16(&As[buf][s*8], Ab + (size_t)gm*lda + kt + gpc*8);
    }
#pragma unroll
    for (int s = tid; s < SLOTSB; s += NT){
      int row = s / PIECES, pc = s % PIECES;
      int gpc = pc ^ (row & PMASK);
      int gn = n0 + row; if (gn > Ndim-1) gn = Ndim-1;
      gld16(&Bs[buf][s*8], Bb + (size_t)gn*ldb + kt + gpc*8);
    }
  };

  if (!skip){
    stage(0, 0);
    __syncthreads();
    int nIter = Kdim / BK;
    int arow = wr*(TM/2) + (lane & 15);
    int brow = wc*(TN/WCG) + (lane & 15);
    int aswz = arow & PMASK;                        // invariant across i (16%PIECES==0)
    int bswz = brow & PMASK;                        // invariant across j (32%PIECES==0)
    for (int it = 0; it < nIter; ++it){
      int cur = it & 1;
      if (it + 1 < nIter) stage((it+1)*BK, cur ^ 1);   // async prefetch overlaps MFMA
      const bf16* Ac = As[cur];
      const bf16* Bc = Bs[cur];
#pragma unroll
      for (int kk = 0; kk < BK; kk += 32){
        bf16x8 af[FI], bfr[FJ];
        int p = (kk >> 3) + (lane >> 4);            // k-piece index
        int aoff = (p ^ aswz) * 8;
        int boff = (p ^ bswz) * 8;
#pragma unroll
        for (int i = 0; i < FI; i++) af[i] = *(const bf16x8*)(Ac + (arow + i*16)*BK + aoff);
#pragma unroll
        for (int j = 0; j < FJ; j++) bfr[j] = *(const bf16x8*)(Bc + (brow + j*16)*BK + boff);
#pragma unroll
        for (int i = 0; i < FI; i++)
#pragma unroll
          for (int j = 0; j < FJ; j++)
            acc[i][j] = __builtin_amdgcn_mfma_f32_16x16x32_bf16(af[i], bfr[j], acc[i][j], 0, 0, 0);
      }
      __syncthreads();
    }
  }

  // epilogue: C/D layout col=lane&15, row=(lane>>4)*4+reg
  float sA = sAp[0];
  float am = 0.0f;
  int colr = lane & 15, rowq = (lane >> 4)*4;
  int chunkId = 0;
  long cBase = offC;
  float postw = post;
  float* amaxS = amax_stripe;
  if (SPLITN){
    chunkId = n0 >> 10;
    cBase = (long)chunkId * oCchunk;
    postw = chunkId ? 1.0f : post;
    amaxS = amax_stripe + chunkId*1024;
  }
#pragma unroll
  for (int j = 0; j < FJ; j++){
    int n = n0 + wc*(TN/WCG) + j*16 + colr;
    int nc = n < Ndim ? n : Ndim-1;
    float sB = sBp[(size_t)nc * (size_t)sBstride];
    float cs = sA * sB * postw;
    float bv = HASBIAS ? bias[nc] : 0.0f;
    int ncol = SPLITN ? (n & 1023) : n;
#pragma unroll
    for (int i = 0; i < FI; i++){
      int mb = m0 + wr*(TM/2) + i*16 + rowq;
#pragma unroll
      for (int r = 0; r < 4; r++){
        int m = mb + r;
        float v = acc[i][j][r]*cs + bv;
        if (RELU) v = fmaxf(v, 0.0f);
        if (CAUSAL && n > m) v = -1e9f;
        if (m < Mdim && n < Ndim){
          size_t ci = (size_t)cBase + (size_t)m*ldc + ncol;
          if (RESID) v += R[ci];
          C[ci] = v;
          if (HASAMAX) am = fmaxf(am, fabsf(v));
        }
      }
    }
  }
  if (HASAMAX){
#pragma unroll
    for (int o = 32; o > 0; o >>= 1) am = fmaxf(am, __shfl_down(am, o));
    if (lane == 0){
      int j = (blockIdx.x*5 + blockIdx.y*11 + blockIdx.z*3 + wid) & 63;
      atomicMaxF(&amaxS[j*16], am);
    }
  }
}

extern "C" void kernel_launch(void* const* d_in, const int* in_sizes, int n_in,
                              void* d_out, int out_size, void* d_ws, size_t ws_size,
                              hipStream_t stream)
{
  (void)in_sizes; (void)n_in; (void)out_size; (void)ws_size;
  const float* targets = (const float*)d_in[0];
  const float* encoded = (const float*)d_in[1];
  const float* ln1_s = (const float*)d_in[4];
  const float* ln1_b = (const float*)d_in[5];
  const float* ln2_s = (const float*)d_in[6];
  const float* ln2_b = (const float*)d_in[7];
  const float* ln3_s = (const float*)d_in[8];
  const float* ln3_b = (const float*)d_in[9];
  const float* Wq_s = (const float*)d_in[10];
  const float* Wk_s = (const float*)d_in[11];
  const float* Wv_s = (const float*)d_in[12];
  const float* Wo_s = (const float*)d_in[13];
  const float* Wq_c = (const float*)d_in[14];
  const float* Wk_c = (const float*)d_in[15];
  const float* Wv_c = (const float*)d_in[16];
  const float* Wo_c = (const float*)d_in[17];
  const float* W1 = (const float*)d_in[18];
  const float* B1 = (const float*)d_in[19];
  const float* W2 = (const float*)d_in[20];
  const float* B2 = (const float*)d_in[21];
  float* OUT = (float*)d_out;

  char* ws = (char*)d_ws;
  const size_t MB = 1ull << 20;
  float* ACT_N = (float*)(ws +   0*MB);   // 16 MB  ln out; attn out
  float* ACT_Q = (float*)(ws +  16*MB);   // 16 MB
  float* ACT_K = (float*)(ws +  32*MB);   // 16 MB
  float* ACT_V = (float*)(ws +  48*MB);   // 16 MB
  float* BIGF  = (float*)(ws +  16*MB);   // 64 MB  mlp hidden (overlays Q/K/V)
  float* PART  = (float*)(ws +  16*MB);   // 32 MB  MLP2 K-split partials (BIGF dead by then)
  float* RES_X = (float*)(ws +  80*MB);   // 16 MB  x, then y (in-place)
  bf16*  XQ    = (bf16*) (ws +  96*MB);   // 32 MB  quantized act / h1
  bf16*  WQb   = (bf16*) (ws + 128*MB);   //  8 MB  quantized transposed weights
  bf16*  AQ    = (bf16*) (ws + 136*MB);   //  8 MB
  bf16*  KQ    = (bf16*) (ws + 144*MB);   //  8 MB
  bf16*  VQT   = (bf16*) (ws + 152*MB);   //  8 MB
  float* ST    = (float*)(ws + 160*MB);   //  1 MB  stripes + scales + row stats

  enum { XN=0, Q1=1, K1=2, V1=3, AO1=4, YN=5, Q2=6, K2=7, V2=8, AO2=9, ZN=10, H1S=11, ENC=12, P1=13, P2=14, MNL_C=17 };
  float* STR  = ST;                       // 18*1024 floats of stripes
  float* scl  = ST + 18432;               // 32 final scales
  float* wsc  = ST + 18496;               // 13312 per-column weight scales
  float* mrow = ST + 32768;
  float* lrow = ST + 98304;
#define STRIPE(s) (STR + (s)*1024)

  const long nAct = (long)NTOK * DIM;   // 4M elems

  init_kernel<<<dim3(128),256,0,stream>>>(ST);

  colamax_kernel<<<dim3( 4, 8),256,0,stream>>>(Wq_s, DIM, DIM, wsc +     0);
  colamax_kernel<<<dim3( 4, 8),256,0,stream>>>(Wk_s, DIM, DIM, wsc +  1024);
  colamax_kernel<<<dim3( 4, 8),256,0,stream>>>(Wv_s, DIM, DIM, wsc +  2048);
  colamax_kernel<<<dim3( 4, 8),256,0,stream>>>(Wo_s, DIM, DIM, wsc +  3072);
  colamax_kernel<<<dim3( 4, 8),256,0,stream>>>(Wq_c, DIM, DIM, wsc +  4096);
  colamax_kernel<<<dim3( 4, 8),256,0,stream>>>(Wk_c, DIM, DIM, wsc +  5120);
  colamax_kernel<<<dim3( 4, 8),256,0,stream>>>(Wv_c, DIM, DIM, wsc +  6144);
  colamax_kernel<<<dim3( 4, 8),256,0,stream>>>(Wo_c, DIM, DIM, wsc +  7168);
  colamax_kernel<<<dim3(16, 8),256,0,stream>>>(W1,   DIM, FF,  wsc +  8192);
  colamax_kernel<<<dim3( 4,32),256,0,stream>>>(W2,   FF,  DIM, wsc + 12288);
  finalize_kernel<<<dim3(52),256,0,stream>>>(wsc, 13312);

  // ================= self attention =================
  ln_kernel<<<dim3(NTOK),256,0,stream>>>(targets, ln1_s, ln1_b, ACT_N, STRIPE(XN));
  quant_kernel<<<dim3(2048),256,0,stream>>>(ACT_N, XQ, STRIPE(XN), &scl[XN], nAct/4);

  // fused QKV weights: wqT rows [0,1024)=Wq, [1024,2048)=Wk, [2048,3072)=Wv
  transq_kernel<<<dim3(32,32),dim3(32,8),0,stream>>>(Wq_s, WQb,             wsc +    0, DIM, DIM);
  transq_kernel<<<dim3(32,32),dim3(32,8),0,stream>>>(Wk_s, WQb + 1024*DIM,  wsc + 1024, DIM, DIM);
  transq_kernel<<<dim3(32,32),dim3(32,8),0,stream>>>(Wv_s, WQb + 2048*DIM,  wsc + 2048, DIM, DIM);
  gemm_kernel<64,128,128,8,0,false,false,false,true,true><<<dim3(24,32,1),512,0,stream>>>(
      XQ, WQb, ACT_Q, nullptr, &scl[XN], wsc + 0, 1, nullptr, 0.125f, STRIPE(Q1),
      NTOK, 3072, DIM, DIM, DIM, DIM, 0,0,0,0,0,0, nAct);

  quant_kernel<<<dim3(2048),256,0,stream>>>(ACT_Q, AQ, STRIPE(Q1), &scl[Q1], nAct/4);
  quant_kernel<<<dim3(2048),256,0,stream>>>(ACT_K, KQ, STRIPE(K1), &scl[K1], nAct/4);
  vtransq_kernel<<<dim3(8,128),dim3(64,8),0,stream>>>(ACT_V, VQT, STRIPE(V1), &scl[V1]);

  // fused causal attention: QK^T + softmax + quant(P) (sp=1/127 exact) + PV
  fattn_kernel<2,true><<<dim3(128,2),512,0,stream>>>(
      AQ, KQ, VQT, ACT_N, nullptr, nullptr,
      &scl[Q1], &scl[K1], &scl[V1], nullptr, STRIPE(AO1));

  quant_kernel<<<dim3(2048),256,0,stream>>>(ACT_N, XQ, STRIPE(AO1), &scl[AO1], nAct/4);
  transq_kernel<<<dim3(32,32),dim3(32,8),0,stream>>>(Wo_s, WQb, wsc + 3072, DIM, DIM);
  gemm_kernel<64,128,64,4,1,false,false,false,false,false><<<dim3(16,32,1),256,0,stream>>>(
      XQ, WQb, RES_X, targets, &scl[AO1], wsc + 3072, 1, nullptr, 1.0f, nullptr,
      NTOK, DIM, DIM, DIM, DIM, DIM, 0,0,0,0,0,0, 0);

  // ================= cross attention =================
  ln_kernel<<<dim3(NTOK),256,0,stream>>>(RES_X, ln2_s, ln2_b, ACT_N, STRIPE(YN));
  quant_kernel<<<dim3(2048),256,0,stream>>>(ACT_N, XQ, STRIPE(YN), &scl[YN], nAct/4);
  amax_kernel<<<dim3(2048),256,0,stream>>>(encoded, nAct, STRIPE(ENC));
  quant_kernel<<<dim3(2048),256,0,stream>>>(encoded, AQ, STRIPE(ENC), &scl[ENC], nAct/4);

  transq_kernel<<<dim3(32,32),dim3(32,8),0,stream>>>(Wq_c, WQb,            wsc + 4096, DIM, DIM);
  transq_kernel<<<dim3(32,32),dim3(32,8),0,stream>>>(Wk_c, WQb + 1024*DIM, wsc + 5120, DIM, DIM);
  transq_kernel<<<dim3(32,32),dim3(32,8),0,stream>>>(Wv_c, WQb + 2048*DIM, wsc + 6144, DIM, DIM);
  gemm_kernel<64,128,64,4,0,false,false,false,true,false><<<dim3(16,32,1),256,0,stream>>>(
      XQ, WQb, ACT_Q, nullptr, &scl[YN], wsc + 4096, 1, nullptr, 0.125f, STRIPE(Q2),
      NTOK, DIM, DIM, DIM, DIM, DIM, 0,0,0,0,0,0, 0);
  // fused KV (A = quantized encoded): chunks -> ACT_K, ACT_V
  gemm_kernel<64,128,128,8,0,false,false,false,true,true><<<dim3(16,32,1),512,0,stream>>>(
      AQ, WQb + 1024*DIM, ACT_K, nullptr, &scl[ENC], wsc + 5120, 1, nullptr, 1.0f, STRIPE(K2),
      NTOK, 2048, DIM, DIM, DIM, DIM, 0,0,0,0,0,0, nAct);

  quant_kernel<<<dim3(2048),256,0,stream>>>(ACT_Q, AQ, STRIPE(Q2), &scl[Q2], nAct/4);
  quant_kernel<<<dim3(2048),256,0,stream>>>(ACT_K, KQ, STRIPE(K2), &scl[K2], nAct/4);
  vtransq_kernel<<<dim3(8,128),dim3(64,8),0,stream>>>(ACT_V, VQT, STRIPE(V2), &scl[V2]);

  // fused cross attention: stats pass -> global min(l) -> final pass
  fattn_kernel<0,false><<<dim3(128,2),512,0,stream>>>(
      AQ, KQ, VQT, nullptr, mrow, lrow,
      &scl[Q2], &scl[K2], nullptr, nullptr, nullptr);
  minl_kernel<<<dim3(64),256,0,stream>>>(lrow, NROW, STRIPE(MNL_C));
  fattn_kernel<1,false><<<dim3(128,2),512,0,stream>>>(
      AQ, KQ, VQT, ACT_N, mrow, lrow,
      &scl[Q2], &scl[K2], &scl[V2], STRIPE(MNL_C), STRIPE(AO2));

  quant_kernel<<<dim3(2048),256,0,stream>>>(ACT_N, XQ, STRIPE(AO2), &scl[AO2], nAct/4);
  transq_kernel<<<dim3(32,32),dim3(32,8),0,stream>>>(Wo_c, WQb, wsc + 7168, DIM, DIM);
  gemm_kernel<64,128,64,4,1,false,false,false,false,false><<<dim3(16,32,1),256,0,stream>>>(
      XQ, WQb, RES_X, RES_X, &scl[AO2], wsc + 7168, 1, nullptr, 1.0f, nullptr,
      NTOK, DIM, DIM, DIM, DIM, DIM, 0,0,0,0,0,0, 0);

  // ================= MLP =================
  ln_kernel<<<dim3(NTOK),256,0,stream>>>(RES_X, ln3_s, ln3_b, ACT_N, STRIPE(ZN));
  quant_kernel<<<dim3(2048),256,0,stream>>>(ACT_N, XQ, STRIPE(ZN), &scl[ZN], nAct/4);
  transq_kernel<<<dim3(128,32),dim3(32,8),0,stream>>>(W1, WQb, wsc + 8192, DIM, FF);
  gemm_kernel<64,128,128,8,0,false,true,true,true,false><<<dim3(32,32,1),512,0,stream>>>(
      XQ, WQb, BIGF, nullptr, &scl[ZN], wsc + 8192, 1, B1, 1.0f, STRIPE(H1S),
      NTOK, FF, DIM, DIM, DIM, FF, 0,0,0,0,0,0, 0);
  quant_kernel<<<dim3(4096),256,0,stream>>>(BIGF, XQ, STRIPE(H1S), &scl[H1S], (long)NTOK*FF/4);
  transq_kernel<<<dim3(32,128),dim3(32,8),0,stream>>>(W2, WQb, wsc + 12288, FF, DIM);
  // K-split MLP2: z in {0,1} handles K-halves via oA2/oB2 = 2048 element
  // offsets (lda=ldb=4096 so the window shifts within each row); partials
  // (already scaled by sA*sB) land at PART + z*4M. BIGF is dead here.
  gemm_kernel<64,128,64,4,0,false,false,false,false,false><<<dim3(16,32,2),256,0,stream>>>(
      XQ, WQb, PART, nullptr, &scl[H1S], wsc + 12288, 1, nullptr, 1.0f, nullptr,
      NTOK, DIM, FF/2, FF, FF, DIM, 0, 2048, 0, 2048, 0, (long)NTOK*DIM, 0);
  addout_kernel<<<dim3(2048),256,0,stream>>>(PART, PART + nAct, RES_X, B2, OUT, nAct/4);
}

// Round 9
// 774.767 us; speedup vs baseline: 1.5569x; 1.5569x over previous
//
// EncoderDecoder1DBlock on MI355X (gfx950).
// Int8 fake-quant reproduced EXACTLY via integer-valued bf16 MFMA GEMMs.
// R17: revert MLP2 K-split (R16 post-mortem: 70us + 32MB partial writes
// + 12us addout > 77us unsplit) -> single fused GEMM again, but at
// TM=TN=64 (32KB LDS -> 5 blocks/CU, 20 waves/CU). Session's causal
// datapoint (R13 vs R14/R15): these K-loops are latency-bound and
// blocks/CU is the lever; XCD row-band swizzle makes the extra A
// re-fetch an L2 hit (FETCH stayed ~compulsory at 57MB).
// Also: colamax was 32 blocks (1/8 of CUs) x 128-row serial scans ->
// 32-row chunks, 4x blocks.
// Everything else unchanged from R16 (passed, absmax 0.0508).
// Workspace: 161 MB.

#include <hip/hip_runtime.h>
#include <hip/hip_bf16.h>

typedef __hip_bfloat16 bf16;
typedef __attribute__((ext_vector_type(8))) short bf16x8;   // 8 bf16 = 4 VGPRs
typedef __attribute__((ext_vector_type(4))) float floatx4;
typedef __attribute__((ext_vector_type(2))) unsigned uintx2;

#define NBATCH 8
#define SEQ    512
#define DIM    1024
#define NHEAD  16
#define DHEAD  64
#define FF     4096
#define NTOK   (NBATCH*SEQ)            // 4096
#define NROW   (NBATCH*NHEAD*SEQ)      // 65536 attention rows

template<bool B> struct BoolC { static constexpr bool value = B; };

__device__ inline void atomicMaxF(float* p, float v){ atomicMax((unsigned int*)p, __float_as_uint(v)); } // v >= 0

// async global->LDS, 16 bytes per lane (LDS dest = wave-uniform base + lane*16)
__device__ inline void gld16(bf16* lds, const bf16* g){
  __builtin_amdgcn_global_load_lds(
      (const __attribute__((address_space(1))) void*)g,
      (__attribute__((address_space(3))) void*)lds, 16, 0, 0);
}

__device__ inline unsigned pack2bf(float a, float b){
  bf16 ha = __float2bfloat16(a), hb = __float2bfloat16(b);
  unsigned short ua, ub;
  __builtin_memcpy(&ua, &ha, 2); __builtin_memcpy(&ub, &hb, 2);
  return ((unsigned)ub << 16) | (unsigned)ua;
}

// ---- 64-way stripe: sub-slot j lives at stripe[j*16] (64B apart) ----
__device__ inline float stripe_max(const float* __restrict__ st){
  float v = st[(threadIdx.x & 63)*16];
#pragma unroll
  for (int o = 32; o > 0; o >>= 1) v = fmaxf(v, __shfl_xor(v, o));
  return v;
}
__device__ inline float stripe_min(const float* __restrict__ st){
  float v = st[(threadIdx.x & 63)*16];
#pragma unroll
  for (int o = 32; o > 0; o >>= 1) v = fminf(v, __shfl_xor(v, o));
  return v;
}

// blockDim.x == 256 assumed (4 waves). OP: 0=sum, 1=max, 2=min
template<int OP>
__device__ inline float block_reduce256(float v){
  __shared__ float red[4];
#pragma unroll
  for (int o = 32; o > 0; o >>= 1){
    float t = __shfl_down(v, o);
    v = OP==0 ? v + t : (OP==1 ? fmaxf(v, t) : fminf(v, t));
  }
  int lane = threadIdx.x & 63, w = threadIdx.x >> 6;
  if (lane == 0) red[w] = v;
  __syncthreads();
  float r = OP==0 ? (red[0]+red[1])+(red[2]+red[3])
          : OP==1 ? fmaxf(fmaxf(red[0],red[1]), fmaxf(red[2],red[3]))
                  : fminf(fminf(red[0],red[1]), fminf(red[2],red[3]));
  __syncthreads();
  return r;
}

// ---- stats init ----
__global__ void init_kernel(float* __restrict__ ST){
  int i = blockIdx.x * 256 + threadIdx.x;
  if (i >= 32768) return;
  ST[i] = (i >= 16384 && i < 18432) ? 3.402823466e38f : 0.0f;
}

// per-column |w| max (raw, atomic across row-chunks of 32)
__global__ void colamax_kernel(const float* __restrict__ w, int K, int N, float* __restrict__ raw){
  int c = blockIdx.x * 256 + threadIdx.x;
  if (c >= N) return;
  int r0 = blockIdx.y * 32;
  float m = 0.0f;
  for (int r = r0; r < r0 + 32; ++r) m = fmaxf(m, fabsf(w[(size_t)r * N + c]));
  atomicMaxF(&raw[c], m);
}

__global__ void finalize_kernel(float* __restrict__ p, int n){
  int i = blockIdx.x * 256 + threadIdx.x;
  if (i < n) p[i] = fmaxf(p[i] * (1.0f/127.0f), 1e-6f);
}

// LayerNorm (row of 1024) + striped amax of output
__global__ void ln_kernel(const float* __restrict__ x, const float* __restrict__ g,
                          const float* __restrict__ bb, float* __restrict__ out,
                          float* __restrict__ stripe){
  int row = blockIdx.x, tid = threadIdx.x;
  const float* xr = x + (size_t)row * DIM;
  float v[4];
#pragma unroll
  for (int i = 0; i < 4; i++) v[i] = xr[tid + i*256];
  float s = (v[0]+v[1]) + (v[2]+v[3]);
  s = block_reduce256<0>(s);
  float mean = s * (1.0f/DIM);
  float sq = 0.f;
#pragma unroll
  for (int i = 0; i < 4; i++){ float d = v[i]-mean; sq += d*d; }
  sq = block_reduce256<0>(sq);
  float inv = 1.0f / sqrtf(sq * (1.0f/DIM) + 1e-6f);
  float am = 0.f;
  float* orow = out + (size_t)row * DIM;
#pragma unroll
  for (int i = 0; i < 4; i++){
    int c = tid + i*256;
    float o = (v[i]-mean)*inv*g[c] + bb[c];
    orow[c] = o;
    am = fmaxf(am, fabsf(o));
  }
  am = block_reduce256<1>(am);
  if (tid == 0) atomicMaxF(&stripe[(blockIdx.x & 63)*16], am);
}

__global__ void amax_kernel(const float* __restrict__ x, long n, float* __restrict__ stripe){
  long i = (long)blockIdx.x * 256 + threadIdx.x;
  long st = (long)gridDim.x * 256;
  float m = 0.f;
  for (; i < n; i += st) m = fmaxf(m, fabsf(x[i]));
  m = block_reduce256<1>(m);
  if (threadIdx.x == 0) atomicMaxF(&stripe[(blockIdx.x & 63)*16], m);
}

// elementwise quantize to integer-valued bf16 (vectorized: 4 elems/thread)
__global__ void quant_kernel(const float* __restrict__ in, bf16* __restrict__ outq,
                             const float* __restrict__ stripe, float* __restrict__ scale_out, long n4){
  float s = fmaxf(stripe_max(stripe) * (1.0f/127.0f), 1e-6f);
  long i = (long)blockIdx.x * 256 + threadIdx.x;
  if (i == 0) scale_out[0] = s;
  long st = (long)gridDim.x * 256;
  for (; i < n4; i += st){
    floatx4 v = ((const floatx4*)in)[i];
    float q[4];
#pragma unroll
    for (int j = 0; j < 4; j++) q[j] = rintf(fminf(fmaxf(v[j] / s, -127.0f), 127.0f));
    uintx2 o; o[0] = pack2bf(q[0], q[1]); o[1] = pack2bf(q[2], q[3]);
    ((uintx2*)outq)[i] = o;
  }
}

// weight quantize + transpose: w[K][N] -> wqT[N][K]
__global__ void transq_kernel(const float* __restrict__ w, bf16* __restrict__ wqT,
                              const float* __restrict__ scales, int K, int N){
  __shared__ float tile[32][33];
  int c0 = blockIdx.x * 32, r0 = blockIdx.y * 32;
  int tx = threadIdx.x, ty = threadIdx.y;   // (32,8)
#pragma unroll
  for (int i = 0; i < 4; i++){
    int r = ty + i*8;
    tile[r][tx] = w[(size_t)(r0 + r) * N + c0 + tx];
  }
  __syncthreads();
#pragma unroll
  for (int i = 0; i < 4; i++){
    int cl = ty + i*8;
    float s = scales[c0 + cl];
    float q = rintf(fminf(fmaxf(tile[tx][cl] / s, -127.0f), 127.0f));
    wqT[(size_t)(c0 + cl) * K + r0 + tx] = __float2bfloat16(q);
  }
}

// V quantize + transpose: v f32 (B,S,H,DH) -> vqT bf16 (B*H, DH, S)
__global__ void vtransq_kernel(const float* __restrict__ v, bf16* __restrict__ vqT,
                               const float* __restrict__ stripe, float* __restrict__ scale_out){
  __shared__ float tile[64][65];
  float s = fmaxf(stripe_max(stripe) * (1.0f/127.0f), 1e-6f);
  int tx = threadIdx.x, ty = threadIdx.y;   // (64,8)
  int bh = blockIdx.y, j0 = blockIdx.x * 64;
  int b = bh >> 4, h = bh & 15;
  if (blockIdx.x == 0 && bh == 0 && tx == 0 && ty == 0) scale_out[0] = s;
#pragma unroll
  for (int i = 0; i < 8; i++){
    int j = j0 + ty + i*8;
    tile[ty + i*8][tx] = v[((size_t)((size_t)b*SEQ + j)*NHEAD + h)*DHEAD + tx];
  }
  __syncthreads();
#pragma unroll
  for (int i = 0; i < 8; i++){
    int d = ty + i*8;
    float q = rintf(fminf(fmaxf(tile[tx][d] / s, -127.0f), 127.0f));
    vqT[((size_t)bh*DHEAD + d)*SEQ + j0 + tx] = __float2bfloat16(q);
  }
}

// reduce min over lrow[0..n) into 64 stripe slots
__global__ void minl_kernel(const float* __restrict__ lrow, int n, float* __restrict__ stripe){
  float v = 3.402823466e38f;
  for (int i = blockIdx.x * 256 + threadIdx.x; i < n; i += 64*256) v = fminf(v, lrow[i]);
  v = block_reduce256<2>(v);
  if (threadIdx.x == 0) stripe[blockIdx.x*16] = v;
}

// =============== fused flash-style quantized attention (bf16 MFMA) =========
// grid (bh=128, half=2): 256 blocks = exactly 1/CU, ONE round. 512 threads
// = 8 waves x 32 Q rows. Block half h covers bands {h, 3-h}: waves 0-3 ->
// band h, waves 4-7 -> band 3-h (causal work per block balanced; the two
// blocks sharing a bh are 128 apart in linear id -> same XCD L2).
// K[512][64] (and V^T[64][512], MODE!=0) LDS-resident, XOR content swizzle
// (<=2-way bank alias = free). Swapped QK^T: K = A-operand, Q (regs) = B
// -> lane's S col = its Q row; row reduce = 2 shfl_xor. 3-pass softmax
// (max / sum / quantize+PV); exp via __expf (hw v_exp; P is integer-
// quantized after exp so 2e-7 rel error is harmless). Per-wave 16-row
// P tile (2KB) reused across jt.
// MODE 2 (self, CAUSAL): sp = 1/127 exactly.
// MODE 0 (cross stats): K-only LDS, writes (m,l) per row.
// MODE 1 (cross PV): stored stats; sp from minl stripe.
template<int MODE, bool CAUSAL>
__global__ __launch_bounds__(512, 2) void fattn_kernel(
    const bf16* __restrict__ Qq, const bf16* __restrict__ Kq,
    const bf16* __restrict__ VT, float* __restrict__ O,
    float* __restrict__ mrow, float* __restrict__ lrow,
    const float* __restrict__ sqp, const float* __restrict__ skp,
    const float* __restrict__ svp, const float* __restrict__ minl_stripe,
    float* __restrict__ amax_stripe)
{
  constexpr int LDSK = SEQ*DHEAD;                    // 32768 elems (64KB)
  constexpr int LDSV = (MODE==0) ? 0 : DHEAD*SEQ;    // 64KB
  constexpr int LDSP = (MODE==0) ? 0 : 8*16*DHEAD;   // 16KB (8 waves x 16x64 x2B)
  __shared__ __align__(16) bf16 smem[LDSK + LDSV + LDSP];
  bf16* Klds = smem;
  bf16* Vlds = smem + LDSK;
  char* Pw   = (char*)(smem + LDSK + LDSV);

  int bh = blockIdx.x, half = blockIdx.y;
  int b = bh >> 4, h = bh & 15;
  int tid = threadIdx.x, lane = tid & 63, w = tid >> 6;
  int l15 = lane & 15, g4 = lane >> 4;

  float sc = sqp[0] * skp[0];                        // logit scale

  // ---- stage K; XOR content swizzle on source ----
  for (int s = tid; s < SEQ*8; s += 512){            // 4096 slots
    int row = s >> 3, pc = s & 7;
    gld16(&Klds[s*8], Kq + ((size_t)(b*SEQ + row))*DIM + h*DHEAD + ((pc ^ (row & 7))<<3));
  }
  if (MODE != 0){
    const bf16* vbh = VT + (size_t)bh*DHEAD*SEQ;
    for (int s = tid; s < DHEAD*64; s += 512){       // 4096 slots
      int row = s >> 6, pc = s & 63;
      gld16(&Vlds[s*8], vbh + (size_t)row*SEQ + ((pc ^ (row & 7))<<3));
    }
  }

  // ---- wave's 32-row base: bands {half, 3-half} ----
  int band = (w < 4) ? half : (3 - half);
  int qb = band*128 + (w & 3)*32;

  // ---- Q fragments (B-operand: lane holds Q row qb+jt*16+l15) ----
  bf16x8 qf[2][2];
#pragma unroll
  for (int jt = 0; jt < 2; jt++)
#pragma unroll
    for (int ks = 0; ks < 2; ks++)
      qf[jt][ks] = *(const bf16x8*)(Qq + ((size_t)(b*SEQ + qb + jt*16 + l15))*DIM
                                       + h*DHEAD + ks*32 + g4*8);

  __syncthreads();                                   // drains global_load_lds

  int nkb   = CAUSAL ? ((qb + 95) >> 6) : (SEQ/64);  // blocks touched
  int kfull = CAUSAL ? (qb >> 6)        : (SEQ/64);  // fully-valid blocks
  int qs0 = qb + l15;                                // seq pos for jt=0 (+16 for jt=1)

  auto computeS = [&](int kb, floatx4 (&sacc)[4][2]){
#pragma unroll
    for (int it = 0; it < 4; it++)
#pragma unroll
      for (int jt = 0; jt < 2; jt++){ floatx4 zv = {0.f,0.f,0.f,0.f}; sacc[it][jt] = zv; }
#pragma unroll
    for (int ks = 0; ks < 2; ks++){
      bf16x8 af[4];
#pragma unroll
      for (int it = 0; it < 4; it++){
        int row = kb*64 + it*16 + l15;
        int pc  = (ks*4 + g4) ^ (row & 7);
        af[it] = *(const bf16x8*)(Klds + row*64 + pc*8);
      }
#pragma unroll
      for (int it = 0; it < 4; it++)
#pragma unroll
        for (int jt = 0; jt < 2; jt++)
          sacc[it][jt] = __builtin_amdgcn_mfma_f32_16x16x32_bf16(af[it], qf[jt][ks], sacc[it][jt], 0, 0, 0);
    }
  };

  float ml[2], ll[2];
  if (MODE != 1){
    // ---- pass 1: raw row max (full blocks unmasked, diagonal masked) ----
    float mr0 = -3.402823466e38f, mr1 = -3.402823466e38f;
    for (int kb = 0; kb < kfull; kb++){
      floatx4 sacc[4][2];
      computeS(kb, sacc);
#pragma unroll
      for (int it = 0; it < 4; it++)
#pragma unroll
        for (int r = 0; r < 4; r++){
          mr0 = fmaxf(mr0, sacc[it][0][r]);
          mr1 = fmaxf(mr1, sacc[it][1][r]);
        }
    }
    for (int kb = kfull; kb < nkb; kb++){
      floatx4 sacc[4][2];
      computeS(kb, sacc);
#pragma unroll
      for (int it = 0; it < 4; it++){
        int key = kb*64 + it*16 + g4*4;
#pragma unroll
        for (int r = 0; r < 4; r++){
          if (key + r <= qs0)      mr0 = fmaxf(mr0, sacc[it][0][r]);
          if (key + r <= qs0 + 16) mr1 = fmaxf(mr1, sacc[it][1][r]);
        }
      }
    }
    mr0 = fmaxf(mr0, __shfl_xor(mr0, 16)); mr0 = fmaxf(mr0, __shfl_xor(mr0, 32));
    mr1 = fmaxf(mr1, __shfl_xor(mr1, 16)); mr1 = fmaxf(mr1, __shfl_xor(mr1, 32));
    ml[0] = sc*mr0; ml[1] = sc*mr1;                  // logit-space max
    // ---- pass 2: row sum of exp ----
    float l0 = 0.f, l1 = 0.f;
    for (int kb = 0; kb < kfull; kb++){
      floatx4 sacc[4][2];
      computeS(kb, sacc);
#pragma unroll
      for (int it = 0; it < 4; it++)
#pragma unroll
        for (int r = 0; r < 4; r++){
          l0 += __expf(sc*sacc[it][0][r] - ml[0]);
          l1 += __expf(sc*sacc[it][1][r] - ml[1]);
        }
    }
    for (int kb = kfull; kb < nkb; kb++){
      floatx4 sacc[4][2];
      computeS(kb, sacc);
#pragma unroll
      for (int it = 0; it < 4; it++){
        int key = kb*64 + it*16 + g4*4;
#pragma unroll
        for (int r = 0; r < 4; r++){
          if (key + r <= qs0)      l0 += __expf(sc*sacc[it][0][r] - ml[0]);
          if (key + r <= qs0 + 16) l1 += __expf(sc*sacc[it][1][r] - ml[1]);
        }
      }
    }
    l0 += __shfl_xor(l0, 16); l0 += __shfl_xor(l0, 32);
    l1 += __shfl_xor(l1, 16); l1 += __shfl_xor(l1, 32);
    ll[0] = l0; ll[1] = l1;
    if (MODE == 0){
      if (g4 == 0){
        int ridx = bh*SEQ + qb + l15;
        mrow[ridx]      = ml[0]; lrow[ridx]      = ll[0];
        mrow[ridx + 16] = ml[1]; lrow[ridx + 16] = ll[1];
      }
      return;
    }
  } else {
    int ridx = bh*SEQ + qb + l15;
    ml[0] = mrow[ridx];      ll[0] = lrow[ridx];
    ml[1] = mrow[ridx + 16]; ll[1] = lrow[ridx + 16];
  }

  // ---- pass 3: quantize P + PV (per-wave 16-row P tile, jt loop) ----
  float sv = svp[0];
  float sp = (MODE == 2) ? (1.0f/127.0f)
           : fmaxf((1.0f/stripe_min(minl_stripe)) * (1.0f/127.0f), 1e-6f);
  float inv0 = 1.0f/ll[0], inv1 = 1.0f/ll[1];        // self path replicates e*inv/sp

  floatx4 oacc[2][4];
#pragma unroll
  for (int i = 0; i < 2; i++)
#pragma unroll
    for (int j = 0; j < 4; j++){ floatx4 zv = {0.f,0.f,0.f,0.f}; oacc[i][j] = zv; }

  char* Pme = Pw + w*(16*128);                       // wave-private 2KB tile

  auto pass3 = [&](int kb, auto mk){
    constexpr bool M = decltype(mk)::value;
    floatx4 sacc[4][2];
    computeS(kb, sacc);
#pragma unroll
    for (int jt = 0; jt < 2; jt++){
      int qsj = qs0 + jt*16;
      float mlj = ml[jt];
      float invj = jt ? inv1 : inv0;
      float llj = ll[jt];
      // quantize + write P[q=l15][key] (16-row tile, XOR piece swizzle)
#pragma unroll
      for (int it = 0; it < 4; it++){
        int k0 = it*16 + g4*4;
        float qv[4];
#pragma unroll
        for (int r = 0; r < 4; r++){
          bool ok = !M || (kb*64 + k0 + r) <= qsj;
          if (ok){
            float e = __expf(sc*sacc[it][jt][r] - mlj);
            float p = (MODE == 2) ? e * invj : e / llj;
            qv[r] = rintf(fminf(p / sp, 127.0f));
          } else qv[r] = 0.0f;
        }
        int bse = l15*128;
        *(unsigned*)(Pme + bse + ((((k0>>3) ^ (l15&7))<<4) | ((k0&7)<<1))) = pack2bf(qv[0], qv[1]);
        int k2 = k0 + 2;
        *(unsigned*)(Pme + bse + ((((k2>>3) ^ (l15&7))<<4) | ((k2&7)<<1))) = pack2bf(qv[2], qv[3]);
      }
      // PV accumulate: A = P (16 q rows), B = V^T (d cols), K = 64 keys
#pragma unroll
      for (int ks = 0; ks < 2; ks++){
        int kp = (ks*4 + g4) ^ (l15 & 7);
        bf16x8 pa = *(const bf16x8*)(Pme + l15*128 + kp*16);
#pragma unroll
        for (int fj = 0; fj < 4; fj++){
          int d = fj*16 + l15;
          int gp = kb*8 + ks*4 + g4;
          bf16x8 vf = *(const bf16x8*)((char*)Vlds + d*1024 + ((gp ^ (d & 7))<<4));
          oacc[jt][fj] = __builtin_amdgcn_mfma_f32_16x16x32_bf16(pa, vf, oacc[jt][fj], 0, 0, 0);
        }
      }
    }
  };
  for (int kb = 0; kb < kfull; kb++) pass3(kb, BoolC<false>{});
  for (int kb = kfull; kb < nkb; kb++) pass3(kb, BoolC<true>{});

  // ---- epilogue: O = oacc * sp * sv, striped amax ----
  float osc = sp * sv;
  float am = 0.0f;
#pragma unroll
  for (int jt = 0; jt < 2; jt++){
    int qrow = qb + jt*16 + g4*4;
#pragma unroll
    for (int fj = 0; fj < 4; fj++){
      int d = fj*16 + l15;
#pragma unroll
      for (int r = 0; r < 4; r++){
        float v = oacc[jt][fj][r] * osc;
        O[((size_t)(b*SEQ + qrow + r))*DIM + h*DHEAD + d] = v;
        am = fmaxf(am, fabsf(v));
      }
    }
  }
#pragma unroll
  for (int o = 32; o > 0; o >>= 1) am = fmaxf(am, __shfl_down(am, o));
  if (lane == 0){
    int j = (blockIdx.x*5 + blockIdx.y*11 + w) & 63;
    atomicMaxF(&amax_stripe[j*16], am);
  }
}

// ------- MFMA GEMM (TM x TN tile, async dbuf, XCD + LDS-XOR swizzled) ------
// WAVES=4: 256 thr, 2x2 wave grid, wave tile (TM/2)x(TN/2)  [R13-proven]
// WAVES=8: 512 thr, 2x4 wave grid, wave tile (TM/2)x(TN/4)  [R15-proven]
// LDS layout: slot (row,pc) holds global piece pc^(row&(PIECES-1)); readers
// apply the inverse so quarter-wave ds_read_b128 banks spread 2-way (free).
template<int BK, int TM, int TN, int WAVES, int RESID, bool CAUSAL, bool RELU, bool HASBIAS, bool HASAMAX, bool SPLITN>
__global__ __launch_bounds__(WAVES*64) void gemm_kernel(
    const bf16* __restrict__ A, const bf16* __restrict__ Bt,
    float* __restrict__ C, const float* __restrict__ R,
    const float* __restrict__ sAp, const float* __restrict__ sBp, int sBstride,
    const float* __restrict__ bias, float post, float* __restrict__ amax_stripe,
    int Mdim, int Ndim, int Kdim, int lda, int ldb, int ldc,
    long oA1, long oA2, long oB1, long oB2, long oC1, long oC2, long oCchunk)
{
  const int NT  = WAVES*64;
  const int WCG = WAVES/2;             // col groups (2 or 4); 2 row groups
  const int FI  = TM/32, FJ = TN/(16*WCG);
  const int PIECES = BK/8;             // 16B pieces per row
  const int PMASK  = PIECES - 1;
  __shared__ __align__(16) bf16 As[2][TM*BK];
  __shared__ __align__(16) bf16 Bs[2][TN*BK];
  int z = blockIdx.z;
  long offA = (long)(z >> 4)*oA1 + (long)(z & 15)*oA2;
  long offB = (long)(z >> 4)*oB1 + (long)(z & 15)*oB2;
  long offC = (long)(z >> 4)*oC1 + (long)(z & 15)*oC2;
  const bf16* Ab = A + offA;
  const bf16* Bb = Bt + offB;
  int tid = threadIdx.x;
  int lane = tid & 63, wid = tid >> 6;
  int wr = wid / WCG, wc = wid % WCG;

  // XCD-aware swizzle: round-robin linear-id -> give XCD k a row band.
  int bx = blockIdx.x, by = blockIdx.y;
  if ((gridDim.y & 7) == 0){
    int lin  = by * gridDim.x + bx;
    int xcd  = lin & 7, slot = lin >> 3;
    int bandH = gridDim.y >> 3;
    by = xcd * bandH + (slot % bandH);
    bx = slot / bandH;
  }
  int m0 = by * TM, n0 = bx * TN;

  floatx4 acc[FI][FJ];
#pragma unroll
  for (int i = 0; i < FI; i++)
#pragma unroll
    for (int j = 0; j < FJ; j++){ floatx4 zv = {0.f,0.f,0.f,0.f}; acc[i][j] = zv; }

  const int SLOTSA = TM*PIECES;
  const int SLOTSB = TN*PIECES;
  bool skip = CAUSAL && (n0 > m0 + TM - 1);

  auto stage = [&](int kt, int buf){
#pragma unroll
    for (int s = tid; s < SLOTSA; s += NT){
      int row = s / PIECES, pc = s % PIECES;
      int gpc = pc ^ (row & PMASK);                 // XOR content swizzle
      int gm = m0 + row; if (gm > Mdim-1) gm = Mdim-1;
      gld16(&As[buf][s*8], Ab + (size_t)gm*lda + kt + gpc*8);
    }
#pragma unroll
    for (int s = tid; s < SLOTSB; s += NT){
      int row = s / PIECES, pc = s % PIECES;
      int gpc = pc ^ (row & PMASK);
      int gn = n0 + row; if (gn > Ndim-1) gn = Ndim-1;
      gld16(&Bs[buf][s*8], Bb + (size_t)gn*ldb + kt + gpc*8);
    }
  };

  if (!skip){
    stage(0, 0);
    __syncthreads();
    int nIter = Kdim / BK;
    int arow = wr*(TM/2) + (lane & 15);
    int brow = wc*(TN/WCG) + (lane & 15);
    int aswz = arow & PMASK;                        // invariant across i (16%PIECES==0)
    int bswz = brow & PMASK;                        // invariant across j (32%PIECES==0)
    for (int it = 0; it < nIter; ++it){
      int cur = it & 1;
      if (it + 1 < nIter) stage((it+1)*BK, cur ^ 1);   // async prefetch overlaps MFMA
      const bf16* Ac = As[cur];
      const bf16* Bc = Bs[cur];
#pragma unroll
      for (int kk = 0; kk < BK; kk += 32){
        bf16x8 af[FI], bfr[FJ];
        int p = (kk >> 3) + (lane >> 4);            // k-piece index
        int aoff = (p ^ aswz) * 8;
        int boff = (p ^ bswz) * 8;
#pragma unroll
        for (int i = 0; i < FI; i++) af[i] = *(const bf16x8*)(Ac + (arow + i*16)*BK + aoff);
#pragma unroll
        for (int j = 0; j < FJ; j++) bfr[j] = *(const bf16x8*)(Bc + (brow + j*16)*BK + boff);
#pragma unroll
        for (int i = 0; i < FI; i++)
#pragma unroll
          for (int j = 0; j < FJ; j++)
            acc[i][j] = __builtin_amdgcn_mfma_f32_16x16x32_bf16(af[i], bfr[j], acc[i][j], 0, 0, 0);
      }
      __syncthreads();
    }
  }

  // epilogue: C/D layout col=lane&15, row=(lane>>4)*4+reg
  float sA = sAp[0];
  float am = 0.0f;
  int colr = lane & 15, rowq = (lane >> 4)*4;
  int chunkId = 0;
  long cBase = offC;
  float postw = post;
  float* amaxS = amax_stripe;
  if (SPLITN){
    chunkId = n0 >> 10;
    cBase = (long)chunkId * oCchunk;
    postw = chunkId ? 1.0f : post;
    amaxS = amax_stripe + chunkId*1024;
  }
#pragma unroll
  for (int j = 0; j < FJ; j++){
    int n = n0 + wc*(TN/WCG) + j*16 + colr;
    int nc = n < Ndim ? n : Ndim-1;
    float sB = sBp[(size_t)nc * (size_t)sBstride];
    float cs = sA * sB * postw;
    float bv = HASBIAS ? bias[nc] : 0.0f;
    int ncol = SPLITN ? (n & 1023) : n;
#pragma unroll
    for (int i = 0; i < FI; i++){
      int mb = m0 + wr*(TM/2) + i*16 + rowq;
#pragma unroll
      for (int r = 0; r < 4; r++){
        int m = mb + r;
        float v = acc[i][j][r]*cs + bv;
        if (RELU) v = fmaxf(v, 0.0f);
        if (CAUSAL && n > m) v = -1e9f;
        if (m < Mdim && n < Ndim){
          size_t ci = (size_t)cBase + (size_t)m*ldc + ncol;
          if (RESID) v += R[ci];
          C[ci] = v;
          if (HASAMAX) am = fmaxf(am, fabsf(v));
        }
      }
    }
  }
  if (HASAMAX){
#pragma unroll
    for (int o = 32; o > 0; o >>= 1) am = fmaxf(am, __shfl_down(am, o));
    if (lane == 0){
      int j = (blockIdx.x*5 + blockIdx.y*11 + blockIdx.z*3 + wid) & 63;
      atomicMaxF(&amaxS[j*16], am);
    }
  }
}

extern "C" void kernel_launch(void* const* d_in, const int* in_sizes, int n_in,
                              void* d_out, int out_size, void* d_ws, size_t ws_size,
                              hipStream_t stream)
{
  (void)in_sizes; (void)n_in; (void)out_size; (void)ws_size;
  const float* targets = (const float*)d_in[0];
  const float* encoded = (const float*)d_in[1];
  const float* ln1_s = (const float*)d_in[4];
  const float* ln1_b = (const float*)d_in[5];
  const float* ln2_s = (const float*)d_in[6];
  const float* ln2_b = (const float*)d_in[7];
  const float* ln3_s = (const float*)d_in[8];
  const float* ln3_b = (const float*)d_in[9];
  const float* Wq_s = (const float*)d_in[10];
  const float* Wk_s = (const float*)d_in[11];
  const float* Wv_s = (const float*)d_in[12];
  const float* Wo_s = (const float*)d_in[13];
  const float* Wq_c = (const float*)d_in[14];
  const float* Wk_c = (const float*)d_in[15];
  const float* Wv_c = (const float*)d_in[16];
  const float* Wo_c = (const float*)d_in[17];
  const float* W1 = (const float*)d_in[18];
  const float* B1 = (const float*)d_in[19];
  const float* W2 = (const float*)d_in[20];
  const float* B2 = (const float*)d_in[21];
  float* OUT = (float*)d_out;

  char* ws = (char*)d_ws;
  const size_t MB = 1ull << 20;
  float* ACT_N = (float*)(ws +   0*MB);   // 16 MB  ln out; attn out
  float* ACT_Q = (float*)(ws +  16*MB);   // 16 MB
  float* ACT_K = (float*)(ws +  32*MB);   // 16 MB
  float* ACT_V = (float*)(ws +  48*MB);   // 16 MB
  float* BIGF  = (float*)(ws +  16*MB);   // 64 MB  mlp hidden (overlays Q/K/V)
  float* RES_X = (float*)(ws +  80*MB);   // 16 MB  x, then y (in-place)
  bf16*  XQ    = (bf16*) (ws +  96*MB);   // 32 MB  quantized act / h1
  bf16*  WQb   = (bf16*) (ws + 128*MB);   //  8 MB  quantized transposed weights
  bf16*  AQ    = (bf16*) (ws + 136*MB);   //  8 MB
  bf16*  KQ    = (bf16*) (ws + 144*MB);   //  8 MB
  bf16*  VQT   = (bf16*) (ws + 152*MB);   //  8 MB
  float* ST    = (float*)(ws + 160*MB);   //  1 MB  stripes + scales + row stats

  enum { XN=0, Q1=1, K1=2, V1=3, AO1=4, YN=5, Q2=6, K2=7, V2=8, AO2=9, ZN=10, H1S=11, ENC=12, P1=13, P2=14, MNL_C=17 };
  float* STR  = ST;                       // 18*1024 floats of stripes
  float* scl  = ST + 18432;               // 32 final scales
  float* wsc  = ST + 18496;               // 13312 per-column weight scales
  float* mrow = ST + 32768;
  float* lrow = ST + 98304;
#define STRIPE(s) (STR + (s)*1024)

  const long nAct = (long)NTOK * DIM;   // 4M elems

  init_kernel<<<dim3(128),256,0,stream>>>(ST);

  colamax_kernel<<<dim3( 4, 32),256,0,stream>>>(Wq_s, DIM, DIM, wsc +     0);
  colamax_kernel<<<dim3( 4, 32),256,0,stream>>>(Wk_s, DIM, DIM, wsc +  1024);
  colamax_kernel<<<dim3( 4, 32),256,0,stream>>>(Wv_s, DIM, DIM, wsc +  2048);
  colamax_kernel<<<dim3( 4, 32),256,0,stream>>>(Wo_s, DIM, DIM, wsc +  3072);
  colamax_kernel<<<dim3( 4, 32),256,0,stream>>>(Wq_c, DIM, DIM, wsc +  4096);
  colamax_kernel<<<dim3( 4, 32),256,0,stream>>>(Wk_c, DIM, DIM, wsc +  5120);
  colamax_kernel<<<dim3( 4, 32),256,0,stream>>>(Wv_c, DIM, DIM, wsc +  6144);
  colamax_kernel<<<dim3( 4, 32),256,0,stream>>>(Wo_c, DIM, DIM, wsc +  7168);
  colamax_kernel<<<dim3(16, 32),256,0,stream>>>(W1,   DIM, FF,  wsc +  8192);
  colamax_kernel<<<dim3( 4,128),256,0,stream>>>(W2,   FF,  DIM, wsc + 12288);
  finalize_kernel<<<dim3(52),256,0,stream>>>(wsc, 13312);

  // ================= self attention =================
  ln_kernel<<<dim3(NTOK),256,0,stream>>>(targets, ln1_s, ln1_b, ACT_N, STRIPE(XN));
  quant_kernel<<<dim3(2048),256,0,stream>>>(ACT_N, XQ, STRIPE(XN), &scl[XN], nAct/4);

  // fused QKV weights: wqT rows [0,1024)=Wq, [1024,2048)=Wk, [2048,3072)=Wv
  transq_kernel<<<dim3(32,32),dim3(32,8),0,stream>>>(Wq_s, WQb,             wsc +    0, DIM, DIM);
  transq_kernel<<<dim3(32,32),dim3(32,8),0,stream>>>(Wk_s, WQb + 1024*DIM,  wsc + 1024, DIM, DIM);
  transq_kernel<<<dim3(32,32),dim3(32,8),0,stream>>>(Wv_s, WQb + 2048*DIM,  wsc + 2048, DIM, DIM);
  gemm_kernel<64,128,128,8,0,false,false,false,true,true><<<dim3(24,32,1),512,0,stream>>>(
      XQ, WQb, ACT_Q, nullptr, &scl[XN], wsc + 0, 1, nullptr, 0.125f, STRIPE(Q1),
      NTOK, 3072, DIM, DIM, DIM, DIM, 0,0,0,0,0,0, nAct);

  quant_kernel<<<dim3(2048),256,0,stream>>>(ACT_Q, AQ, STRIPE(Q1), &scl[Q1], nAct/4);
  quant_kernel<<<dim3(2048),256,0,stream>>>(ACT_K, KQ, STRIPE(K1), &scl[K1], nAct/4);
  vtransq_kernel<<<dim3(8,128),dim3(64,8),0,stream>>>(ACT_V, VQT, STRIPE(V1), &scl[V1]);

  // fused causal attention: QK^T + softmax + quant(P) (sp=1/127 exact) + PV
  fattn_kernel<2,true><<<dim3(128,2),512,0,stream>>>(
      AQ, KQ, VQT, ACT_N, nullptr, nullptr,
      &scl[Q1], &scl[K1], &scl[V1], nullptr, STRIPE(AO1));

  quant_kernel<<<dim3(2048),256,0,stream>>>(ACT_N, XQ, STRIPE(AO1), &scl[AO1], nAct/4);
  transq_kernel<<<dim3(32,32),dim3(32,8),0,stream>>>(Wo_s, WQb, wsc + 3072, DIM, DIM);
  gemm_kernel<64,128,64,4,1,false,false,false,false,false><<<dim3(16,32,1),256,0,stream>>>(
      XQ, WQb, RES_X, targets, &scl[AO1], wsc + 3072, 1, nullptr, 1.0f, nullptr,
      NTOK, DIM, DIM, DIM, DIM, DIM, 0,0,0,0,0,0, 0);

  // ================= cross attention =================
  ln_kernel<<<dim3(NTOK),256,0,stream>>>(RES_X, ln2_s, ln2_b, ACT_N, STRIPE(YN));
  quant_kernel<<<dim3(2048),256,0,stream>>>(ACT_N, XQ, STRIPE(YN), &scl[YN], nAct/4);
  amax_kernel<<<dim3(2048),256,0,stream>>>(encoded, nAct, STRIPE(ENC));
  quant_kernel<<<dim3(2048),256,0,stream>>>(encoded, AQ, STRIPE(ENC), &scl[ENC], nAct/4);

  transq_kernel<<<dim3(32,32),dim3(32,8),0,stream>>>(Wq_c, WQb,            wsc + 4096, DIM, DIM);
  transq_kernel<<<dim3(32,32),dim3(32,8),0,stream>>>(Wk_c, WQb + 1024*DIM, wsc + 5120, DIM, DIM);
  transq_kernel<<<dim3(32,32),dim3(32,8),0,stream>>>(Wv_c, WQb + 2048*DIM, wsc + 6144, DIM, DIM);
  gemm_kernel<64,128,64,4,0,false,false,false,true,false><<<dim3(16,32,1),256,0,stream>>>(
      XQ, WQb, ACT_Q, nullptr, &scl[YN], wsc + 4096, 1, nullptr, 0.125f, STRIPE(Q2),
      NTOK, DIM, DIM, DIM, DIM, DIM, 0,0,0,0,0,0, 0);
  // fused KV (A = quantized encoded): chunks -> ACT_K, ACT_V
  gemm_kernel<64,128,128,8,0,false,false,false,true,true><<<dim3(16,32,1),512,0,stream>>>(
      AQ, WQb + 1024*DIM, ACT_K, nullptr, &scl[ENC], wsc + 5120, 1, nullptr, 1.0f, STRIPE(K2),
      NTOK, 2048, DIM, DIM, DIM, DIM, 0,0,0,0,0,0, nAct);

  quant_kernel<<<dim3(2048),256,0,stream>>>(ACT_Q, AQ, STRIPE(Q2), &scl[Q2], nAct/4);
  quant_kernel<<<dim3(2048),256,0,stream>>>(ACT_K, KQ, STRIPE(K2), &scl[K2], nAct/4);
  vtransq_kernel<<<dim3(8,128),dim3(64,8),0,stream>>>(ACT_V, VQT, STRIPE(V2), &scl[V2]);

  // fused cross attention: stats pass -> global min(l) -> final pass
  fattn_kernel<0,false><<<dim3(128,2),512,0,stream>>>(
      AQ, KQ, VQT, nullptr, mrow, lrow,
      &scl[Q2], &scl[K2], nullptr, nullptr, nullptr);
  minl_kernel<<<dim3(64),256,0,stream>>>(lrow, NROW, STRIPE(MNL_C));
  fattn_kernel<1,false><<<dim3(128,2),512,0,stream>>>(
      AQ, KQ, VQT, ACT_N, mrow, lrow,
      &scl[Q2], &scl[K2], &scl[V2], STRIPE(MNL_C), STRIPE(AO2));

  quant_kernel<<<dim3(2048),256,0,stream>>>(ACT_N, XQ, STRIPE(AO2), &scl[AO2], nAct/4);
  transq_kernel<<<dim3(32,32),dim3(32,8),0,stream>>>(Wo_c, WQb, wsc + 7168, DIM, DIM);
  gemm_kernel<64,128,64,4,1,false,false,false,false,false><<<dim3(16,32,1),256,0,stream>>>(
      XQ, WQb, RES_X, RES_X, &scl[AO2], wsc + 7168, 1, nullptr, 1.0f, nullptr,
      NTOK, DIM, DIM, DIM, DIM, DIM, 0,0,0,0,0,0, 0);

  // ================= MLP =================
  ln_kernel<<<dim3(NTOK),256,0,stream>>>(RES_X, ln3_s, ln3_b, ACT_N, STRIPE(ZN));
  quant_kernel<<<dim3(2048),256,0,stream>>>(ACT_N, XQ, STRIPE(ZN), &scl[ZN], nAct/4);
  transq_kernel<<<dim3(128,32),dim3(32,8),0,stream>>>(W1, WQb, wsc + 8192, DIM, FF);
  gemm_kernel<64,128,128,8,0,false,true,true,true,false><<<dim3(32,32,1),512,0,stream>>>(
      XQ, WQb, BIGF, nullptr, &scl[ZN], wsc + 8192, 1, B1, 1.0f, STRIPE(H1S),
      NTOK, FF, DIM, DIM, DIM, FF, 0,0,0,0,0,0, 0);
  quant_kernel<<<dim3(4096),256,0,stream>>>(BIGF, XQ, STRIPE(H1S), &scl[H1S], (long)NTOK*FF/4);
  transq_kernel<<<dim3(32,128),dim3(32,8),0,stream>>>(W2, WQb, wsc + 12288, FF, DIM);
  // MLP2: single fused GEMM (resid+bias), 64x64 tile -> 32KB LDS ->
  // 5 blocks/CU, grid (16,64) = 1024 blocks for max TLP on the K=4096 loop.
  gemm_kernel<64,64,64,4,1,false,false,true,false,false><<<dim3(16,64,1),256,0,stream>>>(
      XQ, WQb, OUT, RES_X, &scl[H1S], wsc + 12288, 1, B2, 1.0f, nullptr,
      NTOK, DIM, FF, FF, FF, DIM, 0,0,0,0,0,0, 0);
}